// Round 12
// baseline (482.379 us; speedup 1.0000x reference)
//
#include <hip/hip_runtime.h>
#include <math.h>

#define NB 32768
#define KC 4096
#define DD 512
#define DELTA 2.0f

typedef __attribute__((ext_vector_type(8))) short short8;
typedef __attribute__((ext_vector_type(4))) float facc4;

#define AS1 __attribute__((address_space(1)))
#define AS3 __attribute__((address_space(3)))

__device__ __forceinline__ void gll16(const void* g, void* lds) {
    __builtin_amdgcn_global_load_lds((const AS1 unsigned*)g, (AS3 unsigned*)lds,
                                     16, 0, 0);
}

__device__ __forceinline__ unsigned short f2bf(float f) {
    unsigned u = __float_as_uint(f);
    u += 0x7FFFu + ((u >> 16) & 1u);     // RNE
    return (unsigned short)(u >> 16);
}
__device__ __forceinline__ unsigned ordenc(float f) {
    unsigned u = __float_as_uint(f);
    return (u & 0x80000000u) ? ~u : (u | 0x80000000u);
}
__device__ __forceinline__ float orddec(unsigned o) {
    unsigned u = (o & 0x80000000u) ? (o & 0x7FFFFFFFu) : ~o;
    return __uint_as_float(u);
}
// bf16 rounded toward -inf (conservative lower bound of f)
__device__ __forceinline__ unsigned bf16dn(float f) {
    unsigned u = __float_as_uint(f);
    unsigned t = u >> 16;
    if ((u & 0xFFFFu) && (u >> 31)) t += 1;   // negative: away from zero
    return t & 0xFFFFu;
}
__device__ __forceinline__ float bf16dec(unsigned t) {
    return __uint_as_float(t << 16);
}

// ---- A: fp32 -> bf16, tile to [mblk][ks8][128 r][64 d], 8-granule XOR swizzle
// (r10-proven: granule g of row r stored at g ^ (r&7); 0 conflicts measured)
__global__ __launch_bounds__(256) void tileA_kernel(const float* __restrict__ in,
                                                    unsigned short* __restrict__ out) {
    const size_t t = (size_t)blockIdx.x * 256 + threadIdx.x;
    const int row = (int)(t >> 6);
    const int d0  = (int)(t & 63) << 3;
    const int blk = row >> 7, r = row & 127;
    const int ks  = d0 >> 6,  dw = d0 & 63;
    const int g   = dw >> 3;
    const int dws = ((g ^ (r & 7)) << 3);
    const float4* p = (const float4*)(in + (size_t)row * DD + d0);
    float4 a = p[0], b = p[1];
    unsigned q0 = (unsigned)f2bf(a.x) | ((unsigned)f2bf(a.y) << 16);
    unsigned q1 = (unsigned)f2bf(a.z) | ((unsigned)f2bf(a.w) << 16);
    unsigned q2 = (unsigned)f2bf(b.x) | ((unsigned)f2bf(b.y) << 16);
    unsigned q3 = (unsigned)f2bf(b.z) | ((unsigned)f2bf(b.w) << 16);
    const size_t o = (((size_t)blk * 8 + ks) * 128 + r) * 64 + dws;
    *(uint4*)(out + o) = make_uint4(q0, q1, q2, q3);
}

// ---- B: fp32 -> bf16, tile to [nblk][ks16][128 r][32 d], 4-granule XOR swizzle
// (r11-proven: granule g stored at g ^ ((r>>1)&3); 0 conflicts measured)
__global__ __launch_bounds__(256) void tileB_kernel(const float* __restrict__ in,
                                                    unsigned short* __restrict__ out) {
    const size_t t = (size_t)blockIdx.x * 256 + threadIdx.x;
    const int row = (int)(t >> 6);
    const int d0  = (int)(t & 63) << 3;
    const int blk = row >> 7, r = row & 127;
    const int ks  = d0 >> 5,  dw = d0 & 31;
    const int g   = dw >> 3;
    const int dws = ((g ^ ((r >> 1) & 3)) << 3);
    const float4* p = (const float4*)(in + (size_t)row * DD + d0);
    float4 a = p[0], b = p[1];
    unsigned q0 = (unsigned)f2bf(a.x) | ((unsigned)f2bf(a.y) << 16);
    unsigned q1 = (unsigned)f2bf(a.z) | ((unsigned)f2bf(a.w) << 16);
    unsigned q2 = (unsigned)f2bf(b.x) | ((unsigned)f2bf(b.y) << 16);
    unsigned q3 = (unsigned)f2bf(b.z) | ((unsigned)f2bf(b.w) << 16);
    const size_t o = (((size_t)blk * 16 + ks) * 128 + r) * 32 + dws;
    *(uint4*)(out + o) = make_uint4(q0, q1, q2, q3);
}

// ---------------- c_sq[k] = sum_d c[k][d]^2 (fp32) ----------------
__global__ __launch_bounds__(256) void csq_kernel(const float* __restrict__ cent,
                                                  float* __restrict__ csq) {
    const int wid  = threadIdx.x >> 6;
    const int lane = threadIdx.x & 63;
    const int k = (blockIdx.x << 2) + wid;
    const float* row = cent + (size_t)k * DD;
    float s = 0.f;
#pragma unroll
    for (int d = 0; d < DD; d += 64) {
        float v = row[d + lane];
        s = fmaf(v, v, s);
    }
#pragma unroll
    for (int off = 32; off > 0; off >>= 1) s += __shfl_xor(s, off, 64);
    if (lane == 0) csq[k] = s;
}

// ---- A-resident bf16 MFMA GEMM: 1 block per mblk, 512-iter flat pipeline ----
// A panel (128x512 bf16 = 128KB) staged once into LDS; B streamed 8KB/step,
// double-buffered with counted s_waitcnt vmcnt(2) (loads fly across barriers).
// locmin64[row][64] u64 = { ordenc(min):32 | bf16_down(min2):16 | pad | idx:6 }
__global__ __launch_bounds__(256) void gemm_min(
    const unsigned short* __restrict__ xbT, const unsigned short* __restrict__ cbT,
    const float* __restrict__ csq, unsigned long long* __restrict__ locmin64)
{
    __shared__ unsigned short Al[65536];     // 128KB: 8 x [128][64]
    __shared__ unsigned short Bl[2][4096];   // 2 x 8KB: [128][32]

    const int tid = threadIdx.x;
    const int l = tid & 63, w = tid >> 6;
    const int wr = w >> 1, wc = w & 1;
    const int mblk = blockIdx.x;
    const int m0 = mblk * 128;

    const int hi = l >> 4, ln = l & 15;
    const int koB = (hi ^ ((ln >> 1) & 3)) << 3;   // B granule swizzle (r11-proven)

    // ---- prologue: issue B step 0, then the whole A panel; drain; barrier ----
    {
        const unsigned short* gb0 = cbT + w * 1024 + l * 8;
        gll16(gb0,       &Bl[0][w * 1024]);
        gll16(gb0 + 512, &Bl[0][w * 1024 + 512]);
        const unsigned short* ga = xbT + (size_t)mblk * 65536 + w * 16384 + l * 8;
#pragma unroll
        for (int i = 0; i < 32; ++i)
            gll16(ga + i * 512, &Al[w * 16384 + i * 512]);
        asm volatile("s_waitcnt vmcnt(0)\ns_barrier" ::: "memory");
    }

#pragma unroll 1
    for (int nb = 0; nb < 32; ++nb) {
        const int n0 = nb * 128;

        facc4 acc[4][4];
#pragma unroll
        for (int fr = 0; fr < 4; ++fr)
#pragma unroll
            for (int fc = 0; fc < 4; ++fc) {
                facc4 z = {0.f, 0.f, 0.f, 0.f};
                acc[fr][fc] = z;
            }

#pragma unroll 2
        for (int k = 0; k < 16; ++k) {
            const int t  = nb * 16 + k;
            const int tn = (t + 1) & 511;          // wraps at end: dummy restage
            // ---- stage next B step (2 x 1KB contiguous per wave) ----
            const unsigned short* gs = cbT + (size_t)tn * 4096 + w * 1024 + l * 8;
            gll16(gs,       &Bl[(t + 1) & 1][w * 1024]);
            gll16(gs + 512, &Bl[(t + 1) & 1][w * 1024 + 512]);
            // wait current step's B (issued last iter; flew during compute)
            asm volatile("s_waitcnt vmcnt(2)\ns_barrier" ::: "memory");

            // ---- compute: A frags from resident LDS, B from current buf ----
            const unsigned short* Ak = Al + (k >> 1) * 8192;
            const int koA = (((k & 1) * 4 + hi) ^ (ln & 7)) << 3;
            short8 av[4], bv[4];
#pragma unroll
            for (int fr = 0; fr < 4; ++fr)
                av[fr] = *(const short8*)&Ak[(wr * 64 + fr * 16 + ln) * 64 + koA];
#pragma unroll
            for (int fc = 0; fc < 4; ++fc)
                bv[fc] = *(const short8*)&Bl[t & 1][(wc * 64 + fc * 16 + ln) * 32 + koB];
#pragma unroll
            for (int fr = 0; fr < 4; ++fr)
#pragma unroll
                for (int fc = 0; fc < 4; ++fc)
                    acc[fr][fc] = __builtin_amdgcn_mfma_f32_16x16x32_bf16(
                        av[fr], bv[fc], acc[fr][fc], 0, 0, 0);
            // protect current buf before next iteration's stage overwrites peer
            asm volatile("s_barrier" ::: "memory");
        }

        // ---- epilogue (r11-proven): per (row, 64-col group) min/min2/idx ----
        const int grp = nb * 2 + wc;
#pragma unroll
        for (int fr = 0; fr < 4; ++fr) {
#pragma unroll
            for (int j = 0; j < 4; ++j) {
                float m1 = INFINITY, m2 = INFINITY;
                int ix = 0;
#pragma unroll
                for (int fc = 0; fc < 4; ++fc) {
                    const float d = fmaf(-2.f, acc[fr][fc][j],
                                         csq[n0 + wc * 64 + fc * 16 + ln]);
                    if (d < m1) { m2 = m1; m1 = d; ix = fc * 16 + ln; }
                    else        { m2 = fminf(m2, d); }
                }
#pragma unroll
                for (int off = 1; off < 16; off <<= 1) {
                    const float om1 = __shfl_xor(m1, off, 64);
                    const float om2 = __shfl_xor(m2, off, 64);
                    const int   oix = __shfl_xor(ix, off, 64);
                    if (om1 < m1) { m2 = fminf(m1, om2); m1 = om1; ix = oix; }
                    else          { m2 = fminf(m2, om1); }
                }
                if (ln == 0) {
                    const int row = m0 + wr * 64 + fr * 16 + hi * 4 + j;
                    const unsigned lo = (bf16dn(m2) << 16) | (unsigned)ix;
                    locmin64[(size_t)row * 64 + grp] =
                        ((unsigned long long)ordenc(m1) << 32) | lo;
                }
            }
        }
    }
}

// ---- fused rowthr+qualify+rescue+finalize: one wave per row, zero atomics ----
__global__ __launch_bounds__(256) void rescue_argmin_kernel(
    const float* __restrict__ x, const float* __restrict__ cent,
    const float* __restrict__ csq,
    const unsigned long long* __restrict__ locmin64, int* __restrict__ out)
{
    const int row = blockIdx.x * 4 + (threadIdx.x >> 6);
    const int l = threadIdx.x & 63;

    const unsigned long long e = locmin64[(size_t)row * 64 + l];

    unsigned long long v = e;
#pragma unroll
    for (int off = 32; off > 0; off >>= 1) {
        const unsigned long long o = __shfl_xor(v, off, 64);
        v = (o < v) ? o : v;
    }
    const float thr = orddec((unsigned)(v >> 32)) + DELTA;
    unsigned long long qmask = __ballot((unsigned)(e >> 32) <= ordenc(thr));

    const float4* xr = (const float4*)(x + (size_t)row * DD);
    const float4 a0 = xr[l * 2];
    const float4 a1 = xr[l * 2 + 1];

    unsigned long long best = ~0ull;
    while (qmask) {
        const int g = (int)__ffsll((long long)qmask) - 1;
        qmask &= qmask - 1;
        const unsigned long long eg = __shfl(e, g, 64);
        const float m2 = bf16dec((unsigned)(eg >> 16) & 0xFFFFu);
        if (m2 > thr) {
            const int col = g * 64 + (int)(eg & 63u);
            const float4* cr = (const float4*)(cent + (size_t)col * DD);
            const float4 b0 = cr[l * 2], b1 = cr[l * 2 + 1];
            float s = 0.f;
            s = fmaf(a0.x, b0.x, s); s = fmaf(a0.y, b0.y, s);
            s = fmaf(a0.z, b0.z, s); s = fmaf(a0.w, b0.w, s);
            s = fmaf(a1.x, b1.x, s); s = fmaf(a1.y, b1.y, s);
            s = fmaf(a1.z, b1.z, s); s = fmaf(a1.w, b1.w, s);
#pragma unroll
            for (int off = 1; off < 64; off <<= 1) s += __shfl_xor(s, off, 64);
            const float dist = fmaf(-2.f, s, csq[col]);
            const unsigned long long key =
                ((unsigned long long)ordenc(dist) << 32) | (unsigned)col;
            best = (key < best) ? key : best;
        } else {
            const int cl = l >> 1, sg = l & 1;
            const float4* xh = (const float4*)(x + (size_t)row * DD + sg * 256);
            unsigned long long kb = ~0ull;
#pragma unroll
            for (int pass = 0; pass < 2; ++pass) {
                const int col = g * 64 + pass * 32 + cl;
                const float4* ch = (const float4*)(cent + (size_t)col * DD + sg * 256);
                float s0 = 0.f, s1 = 0.f, s2 = 0.f, s3 = 0.f;
#pragma unroll 8
                for (int ee = 0; ee < 64; ++ee) {
                    const float4 a = xh[ee], b = ch[ee];
                    s0 = fmaf(a.x, b.x, s0);
                    s1 = fmaf(a.y, b.y, s1);
                    s2 = fmaf(a.z, b.z, s2);
                    s3 = fmaf(a.w, b.w, s3);
                }
                float s = (s0 + s1) + (s2 + s3);
                s += __shfl_xor(s, 1, 64);
                const float dist = fmaf(-2.f, s, csq[col]);
                const unsigned long long key =
                    ((unsigned long long)ordenc(dist) << 32) | (unsigned)col;
                kb = (key < kb) ? key : kb;
            }
#pragma unroll
            for (int off = 1; off < 64; off <<= 1) {
                const unsigned long long o = __shfl_xor(kb, off, 64);
                kb = (o < kb) ? o : kb;
            }
            best = (kb < best) ? kb : best;
        }
    }
    if (l == 0) out[row] = (int)(best & 0xFFFFFFFFull);
}

// ---------------- fallback: round-1 fp32 kernel (proven) ----------------
__global__ __launch_bounds__(256) void argmin_fp32_kernel(
        const float* __restrict__ x, const float* __restrict__ cent,
        const float* __restrict__ csq, int* __restrict__ out) {
    __shared__ float xs[16][68];
    __shared__ float cs[16][132];
    const int tid = threadIdx.x;
    const int tx = tid & 15;
    const int ty = tid >> 4;
    const int m0 = blockIdx.x * 64;
    const int srow = tid >> 2;
    const int scol = (tid & 3) << 2;
    const float* xg  = x + (size_t)(m0 + srow) * DD + scol;
    const float* cgA = cent + (size_t)srow * DD + scol;
    const float* cgB = cent + (size_t)(srow + 64) * DD + scol;
    float best[4];
    int bidx[4];
#pragma unroll
    for (int i = 0; i < 4; ++i) { best[i] = INFINITY; bidx[i] = 0; }
    for (int n0 = 0; n0 < KC; n0 += 128) {
        float acc[4][2][4];
#pragma unroll
        for (int i = 0; i < 4; ++i)
#pragma unroll
            for (int h = 0; h < 2; ++h)
#pragma unroll
                for (int j = 0; j < 4; ++j) acc[i][h][j] = 0.f;
        const size_t nOff = (size_t)n0 * DD;
        float4 rx = *(const float4*)(xg);
        float4 rc0 = *(const float4*)(cgA + nOff);
        float4 rc1 = *(const float4*)(cgB + nOff);
        for (int k0 = 0; k0 < DD; k0 += 16) {
            __syncthreads();
            const float* p = (const float*)&rx;
            xs[scol + 0][srow] = p[0]; xs[scol + 1][srow] = p[1];
            xs[scol + 2][srow] = p[2]; xs[scol + 3][srow] = p[3];
            const float* q0 = (const float*)&rc0;
            cs[scol + 0][srow] = q0[0]; cs[scol + 1][srow] = q0[1];
            cs[scol + 2][srow] = q0[2]; cs[scol + 3][srow] = q0[3];
            const float* q1 = (const float*)&rc1;
            cs[scol + 0][srow + 64] = q1[0]; cs[scol + 1][srow + 64] = q1[1];
            cs[scol + 2][srow + 64] = q1[2]; cs[scol + 3][srow + 64] = q1[3];
            __syncthreads();
            if (k0 + 16 < DD) {
                rx  = *(const float4*)(xg + k0 + 16);
                rc0 = *(const float4*)(cgA + nOff + k0 + 16);
                rc1 = *(const float4*)(cgB + nOff + k0 + 16);
            }
#pragma unroll
            for (int dd = 0; dd < 16; ++dd) {
                float4 av  = *(const float4*)&xs[dd][ty << 2];
                float4 bv0 = *(const float4*)&cs[dd][tx << 2];
                float4 bv1 = *(const float4*)&cs[dd][64 + (tx << 2)];
                const float* a  = (const float*)&av;
                const float* b0 = (const float*)&bv0;
                const float* b1 = (const float*)&bv1;
#pragma unroll
                for (int i = 0; i < 4; ++i)
#pragma unroll
                    for (int j = 0; j < 4; ++j) {
                        acc[i][0][j] = fmaf(a[i], b0[j], acc[i][0][j]);
                        acc[i][1][j] = fmaf(a[i], b1[j], acc[i][1][j]);
                    }
            }
        }
        float4 qv0 = *(const float4*)(csq + n0 + (tx << 2));
        float4 qv1 = *(const float4*)(csq + n0 + 64 + (tx << 2));
        const float* q0 = (const float*)&qv0;
        const float* q1 = (const float*)&qv1;
#pragma unroll
        for (int i = 0; i < 4; ++i)
#pragma unroll
            for (int h = 0; h < 2; ++h)
#pragma unroll
                for (int j = 0; j < 4; ++j) {
                    float qq = (h == 0) ? q0[j] : q1[j];
                    float dist = fmaf(-2.f, acc[i][h][j], qq);
                    int kk = n0 + h * 64 + (tx << 2) + j;
                    if (dist < best[i] || (dist == best[i] && kk < bidx[i])) {
                        best[i] = dist; bidx[i] = kk;
                    }
                }
    }
#pragma unroll
    for (int off = 1; off < 16; off <<= 1)
#pragma unroll
        for (int i = 0; i < 4; ++i) {
            float ov = __shfl_xor(best[i], off, 64);
            int oi = __shfl_xor(bidx[i], off, 64);
            if (ov < best[i] || (ov == best[i] && oi < bidx[i])) {
                best[i] = ov; bidx[i] = oi;
            }
        }
    if (tx == 0)
#pragma unroll
        for (int i = 0; i < 4; ++i) out[m0 + (ty << 2) + i] = bidx[i];
}

extern "C" void kernel_launch(void* const* d_in, const int* in_sizes, int n_in,
                              void* d_out, int out_size, void* d_ws, size_t ws_size,
                              hipStream_t stream) {
    const float* x    = (const float*)d_in[0];
    const float* cent = (const float*)d_in[1];
    int* out = (int*)d_out;

    const size_t xb_bytes     = (size_t)NB * DD * 2;        // 32MB
    const size_t cb_bytes     = (size_t)KC * DD * 2;        // 4MB
    const size_t locmin_bytes = (size_t)NB * 64 * 8;        // 16MB (u64)
    const size_t csq_bytes    = (size_t)KC * 4;             // 16KB
    const size_t need = xb_bytes + cb_bytes + locmin_bytes + csq_bytes;

    if (ws_size >= need) {
        char* p = (char*)d_ws;
        unsigned short* xbT = (unsigned short*)p;              p += xb_bytes;
        unsigned short* cbT = (unsigned short*)p;              p += cb_bytes;
        unsigned long long* locmin64 = (unsigned long long*)p; p += locmin_bytes;
        float* csq = (float*)p;

        tileA_kernel<<<NB * DD / 8 / 256, 256, 0, stream>>>(x, xbT);
        tileB_kernel<<<KC * DD / 8 / 256, 256, 0, stream>>>(cent, cbT);
        csq_kernel<<<KC / 4, 256, 0, stream>>>(cent, csq);
        gemm_min<<<NB / 128, 256, 0, stream>>>(xbT, cbT, csq, locmin64);
        rescue_argmin_kernel<<<NB / 4, 256, 0, stream>>>(x, cent, csq, locmin64, out);
    } else {
        float* csq = (float*)d_ws;
        csq_kernel<<<KC / 4, 256, 0, stream>>>(cent, csq);
        argmin_fp32_kernel<<<NB / 64, 256, 0, stream>>>(x, cent, csq, out);
    }
}

// Round 13
// 268.534 us; speedup vs baseline: 1.7963x; 1.7963x over previous
//
#include <hip/hip_runtime.h>
#include <math.h>

#define NB 32768
#define KC 4096
#define DD 512
#define DELTA 2.0f

typedef __attribute__((ext_vector_type(8))) short short8;
typedef __attribute__((ext_vector_type(4))) float facc4;

#define AS1 __attribute__((address_space(1)))
#define AS3 __attribute__((address_space(3)))

__device__ __forceinline__ void gll16(const void* g, void* lds) {
    __builtin_amdgcn_global_load_lds((const AS1 unsigned*)g, (AS3 unsigned*)lds,
                                     16, 0, 0);
}

__device__ __forceinline__ unsigned short f2bf(float f) {
    unsigned u = __float_as_uint(f);
    u += 0x7FFFu + ((u >> 16) & 1u);     // RNE
    return (unsigned short)(u >> 16);
}
__device__ __forceinline__ unsigned ordenc(float f) {
    unsigned u = __float_as_uint(f);
    return (u & 0x80000000u) ? ~u : (u | 0x80000000u);
}
__device__ __forceinline__ float orddec(unsigned o) {
    unsigned u = (o & 0x80000000u) ? (o & 0x7FFFFFFFu) : ~o;
    return __uint_as_float(u);
}
// bf16 rounded toward -inf (conservative lower bound of f)
__device__ __forceinline__ unsigned bf16dn(float f) {
    unsigned u = __float_as_uint(f);
    unsigned t = u >> 16;
    if ((u & 0xFFFFu) && (u >> 31)) t += 1;
    return t & 0xFFFFu;
}
__device__ __forceinline__ float bf16dec(unsigned t) {
    return __uint_as_float(t << 16);
}

// ---- A: fp32 -> bf16, tile to [mb(256rows)][ks8][kk2][256 r][32 d] ----
// 4-granule XOR swizzle (r11-proven, 0 conflicts): granule g at g ^ ((r>>1)&3)
__global__ __launch_bounds__(256) void tileA_kernel(const float* __restrict__ in,
                                                    unsigned short* __restrict__ out) {
    const size_t t = (size_t)blockIdx.x * 256 + threadIdx.x;
    const int row = (int)(t >> 6);
    const int d0  = (int)(t & 63) << 3;
    const int mb = row >> 8, r = row & 255;
    const int ks = d0 >> 6, kk = (d0 & 63) >> 5, dw = d0 & 31;
    const int g  = dw >> 3;
    const int dws = ((g ^ ((r >> 1) & 3)) << 3);
    const float4* p = (const float4*)(in + (size_t)row * DD + d0);
    float4 a = p[0], b = p[1];
    unsigned q0 = (unsigned)f2bf(a.x) | ((unsigned)f2bf(a.y) << 16);
    unsigned q1 = (unsigned)f2bf(a.z) | ((unsigned)f2bf(a.w) << 16);
    unsigned q2 = (unsigned)f2bf(b.x) | ((unsigned)f2bf(b.y) << 16);
    unsigned q3 = (unsigned)f2bf(b.z) | ((unsigned)f2bf(b.w) << 16);
    const size_t o = (((size_t)((mb * 8 + ks) * 2 + kk)) * 256 + r) * 32 + dws;
    *(uint4*)(out + o) = make_uint4(q0, q1, q2, q3);
}

// ---- B: same layout for centroids: [nb(256cols)][ks8][kk2][256][32] ----
__global__ __launch_bounds__(256) void tileB_kernel(const float* __restrict__ in,
                                                    unsigned short* __restrict__ out) {
    const size_t t = (size_t)blockIdx.x * 256 + threadIdx.x;
    const int row = (int)(t >> 6);
    const int d0  = (int)(t & 63) << 3;
    const int nb = row >> 8, r = row & 255;
    const int ks = d0 >> 6, kk = (d0 & 63) >> 5, dw = d0 & 31;
    const int g  = dw >> 3;
    const int dws = ((g ^ ((r >> 1) & 3)) << 3);
    const float4* p = (const float4*)(in + (size_t)row * DD + d0);
    float4 a = p[0], b = p[1];
    unsigned q0 = (unsigned)f2bf(a.x) | ((unsigned)f2bf(a.y) << 16);
    unsigned q1 = (unsigned)f2bf(a.z) | ((unsigned)f2bf(a.w) << 16);
    unsigned q2 = (unsigned)f2bf(b.x) | ((unsigned)f2bf(b.y) << 16);
    unsigned q3 = (unsigned)f2bf(b.z) | ((unsigned)f2bf(b.w) << 16);
    const size_t o = (((size_t)((nb * 8 + ks) * 2 + kk)) * 256 + r) * 32 + dws;
    *(uint4*)(out + o) = make_uint4(q0, q1, q2, q3);
}

// ---------------- c_sq[k] = sum_d c[k][d]^2 (fp32) ----------------
__global__ __launch_bounds__(256) void csq_kernel(const float* __restrict__ cent,
                                                  float* __restrict__ csq) {
    const int wid  = threadIdx.x >> 6;
    const int lane = threadIdx.x & 63;
    const int k = (blockIdx.x << 2) + wid;
    const float* row = cent + (size_t)k * DD;
    float s = 0.f;
#pragma unroll
    for (int d = 0; d < DD; d += 64) {
        float v = row[d + lane];
        s = fmaf(v, v, s);
    }
#pragma unroll
    for (int off = 32; off > 0; off >>= 1) s += __shfl_xor(s, off, 64);
    if (lane == 0) csq[k] = s;
}

// ---- 8-phase 256x256 bf16 MFMA GEMM (T3+T4+T5), 8 waves, 128KB LDS ----
// locmin64[row][64] u64 = { ordenc(min):32 | bf16_down(min2):16 | pad | idx:6 }
__global__ __launch_bounds__(512, 2) void gemm_min(
    const unsigned short* __restrict__ xbT, const unsigned short* __restrict__ cbT,
    const float* __restrict__ csq, unsigned long long* __restrict__ locmin64)
{
    __shared__ unsigned short Al[2][2][8192];   // [buf][kkhalf][256r x 32d] 64KB
    __shared__ unsigned short Bl[2][2][8192];   // 64KB

    const int tid = threadIdx.x;
    const int l = tid & 63, w = tid >> 6;       // 8 waves
    const int wm = w >> 2, wn = w & 3;          // 2M x 4N wave grid
    const int hi = l >> 4, ln = l & 15;
    const int koh = (hi ^ ((ln & 7) >> 1)) << 3;

    const int bid = blockIdx.x;
    const int swz = (bid & 7) * 256 + (bid >> 3);   // bijective XCD swizzle
    const int nb = swz >> 7, mb = swz & 127;

    const int aoff = (wm * 128 + ln) * 32 + koh;
    const int boff = (wn * 64 + ln) * 32 + koh;

#define SA(ks_, kk_) do {                                                     \
    const unsigned short* s_ = xbT +                                          \
        ((size_t)((mb * 8 + (ks_)) * 2 + (kk_))) * 8192 + w * 512 + l * 8;    \
    unsigned short* d_ = &Al[(ks_) & 1][(kk_)][w * 512];                      \
    gll16(s_, d_); gll16(s_ + 4096, d_ + 4096); } while (0)
#define SB(ks_, kk_) do {                                                     \
    const unsigned short* s_ = cbT +                                          \
        ((size_t)((nb * 8 + (ks_)) * 2 + (kk_))) * 8192 + w * 512 + l * 8;    \
    unsigned short* d_ = &Bl[(ks_) & 1][(kk_)][w * 512];                      \
    gll16(s_, d_); gll16(s_ + 4096, d_ + 4096); } while (0)
#define BAR  asm volatile("s_barrier" ::: "memory")
#define VBAR asm volatile("s_waitcnt vmcnt(6)\ns_barrier" ::: "memory")

    facc4 acc[8][4];
#pragma unroll
    for (int fr = 0; fr < 8; ++fr)
#pragma unroll
        for (int fc = 0; fc < 4; ++fc) {
            facc4 z = {0.f, 0.f, 0.f, 0.f};
            acc[fr][fc] = z;
        }

    // prologue: K0 fully + K1 {Bkk0, Akk0, Bkk1}; K1.Akk1 comes at K0.p0
    SA(0, 0); SB(0, 0); SA(0, 1); SB(0, 1);
    SB(1, 0); SA(1, 0); SB(1, 1);
    VBAR;   // K0 landed; 3 halves of K1 in flight

    short8 bv[4];

#define LOADA(b_, kk_, frb_)                                                  \
    _Pragma("unroll")                                                         \
    for (int f2 = 0; f2 < 4; ++f2)                                            \
        av[f2] = *(const short8*)&Al[b_][kk_][aoff + ((frb_) + f2) * 512];
#define LOADB(b_, kk_)                                                        \
    _Pragma("unroll")                                                         \
    for (int fc = 0; fc < 4; ++fc)                                            \
        bv[fc] = *(const short8*)&Bl[b_][kk_][boff + fc * 512];
#define MFMA16(frb_)                                                          \
    __builtin_amdgcn_s_setprio(1);                                            \
    _Pragma("unroll")                                                         \
    for (int f2 = 0; f2 < 4; ++f2)                                            \
        _Pragma("unroll")                                                     \
        for (int fc = 0; fc < 4; ++fc)                                        \
            acc[(frb_) + f2][fc] = __builtin_amdgcn_mfma_f32_16x16x32_bf16(   \
                av[f2], bv[fc], acc[(frb_) + f2][fc], 0, 0, 0);               \
    __builtin_amdgcn_s_setprio(0);

#pragma unroll 1
    for (int kp = 0; kp < 4; ++kp) {
        const bool st = (kp < 3);
        const int ks0 = 2 * kp;
        // ======== K-tile ks0 (buf 0) ========
        { short8 av[4]; LOADA(0, 0, 0) LOADB(0, 0)       // p0
          SA(ks0 + 1, 1);                                // completes K-tile ks0+1
          BAR; MFMA16(0) BAR; }
        { short8 av[4]; LOADA(0, 0, 4)                   // p1 (bv reuse)
          if (st) SB(ks0 + 2, 0);
          BAR; MFMA16(4) BAR; }
        { short8 av[4]; LOADA(0, 1, 0) LOADB(0, 1)       // p2
          if (st) SA(ks0 + 2, 0);
          BAR; MFMA16(0) BAR; }
        { short8 av[4]; LOADA(0, 1, 4)                   // p3
          if (st) SB(ks0 + 2, 1);
          BAR; MFMA16(4) VBAR; }                         // next K-tile ready
        // ======== K-tile ks0+1 (buf 1) ========
        { short8 av[4]; LOADA(1, 0, 0) LOADB(1, 0)       // p4
          if (st) SA(ks0 + 2, 1);
          BAR; MFMA16(0) BAR; }
        { short8 av[4]; LOADA(1, 0, 4)                   // p5
          if (st) SB(ks0 + 3, 0);
          BAR; MFMA16(4) BAR; }
        { short8 av[4]; LOADA(1, 1, 0) LOADB(1, 1)       // p6
          if (st) SA(ks0 + 3, 0);
          BAR; MFMA16(0) BAR; }
        { short8 av[4]; LOADA(1, 1, 4)                   // p7
          if (st) SB(ks0 + 3, 1);
          BAR; MFMA16(4) VBAR; }
    }

    // ---- epilogue (r10-validated): per (row, 64-col group) min/min2/idx ----
    const int n0 = nb * 256;
    const int grp = nb * 4 + wn;
    float cs4[4];
#pragma unroll
    for (int fc = 0; fc < 4; ++fc) cs4[fc] = csq[n0 + wn * 64 + fc * 16 + ln];

#pragma unroll
    for (int fr = 0; fr < 8; ++fr) {
#pragma unroll
        for (int j = 0; j < 4; ++j) {
            float m1 = INFINITY, m2 = INFINITY;
            int ix = 0;
#pragma unroll
            for (int fc = 0; fc < 4; ++fc) {
                const float d = fmaf(-2.f, acc[fr][fc][j], cs4[fc]);
                if (d < m1) { m2 = m1; m1 = d; ix = fc * 16 + ln; }
                else        { m2 = fminf(m2, d); }
            }
#pragma unroll
            for (int off = 1; off < 16; off <<= 1) {
                const float om1 = __shfl_xor(m1, off, 64);
                const float om2 = __shfl_xor(m2, off, 64);
                const int   oix = __shfl_xor(ix, off, 64);
                if (om1 < m1) { m2 = fminf(m1, om2); m1 = om1; ix = oix; }
                else          { m2 = fminf(m2, om1); }
            }
            if (ln == 0) {
                const int row = mb * 256 + wm * 128 + fr * 16 + hi * 4 + j;
                const unsigned lo = (bf16dn(m2) << 16) | (unsigned)ix;
                locmin64[(size_t)row * 64 + grp] =
                    ((unsigned long long)ordenc(m1) << 32) | lo;
            }
        }
    }
#undef SA
#undef SB
#undef BAR
#undef VBAR
#undef LOADA
#undef LOADB
#undef MFMA16
}

// ---- fused rowthr+qualify+rescue+finalize: one wave per row, zero atomics ----
__global__ __launch_bounds__(256) void rescue_argmin_kernel(
    const float* __restrict__ x, const float* __restrict__ cent,
    const float* __restrict__ csq,
    const unsigned long long* __restrict__ locmin64, int* __restrict__ out)
{
    const int row = blockIdx.x * 4 + (threadIdx.x >> 6);
    const int l = threadIdx.x & 63;

    const unsigned long long e = locmin64[(size_t)row * 64 + l];

    unsigned long long v = e;
#pragma unroll
    for (int off = 32; off > 0; off >>= 1) {
        const unsigned long long o = __shfl_xor(v, off, 64);
        v = (o < v) ? o : v;
    }
    const float thr = orddec((unsigned)(v >> 32)) + DELTA;
    unsigned long long qmask = __ballot((unsigned)(e >> 32) <= ordenc(thr));

    const float4* xr = (const float4*)(x + (size_t)row * DD);
    const float4 a0 = xr[l * 2];
    const float4 a1 = xr[l * 2 + 1];

    unsigned long long best = ~0ull;
    while (qmask) {
        const int g = (int)__ffsll((long long)qmask) - 1;
        qmask &= qmask - 1;
        const unsigned long long eg = __shfl(e, g, 64);
        const float m2 = bf16dec((unsigned)(eg >> 16) & 0xFFFFu);
        if (m2 > thr) {
            const int col = g * 64 + (int)(eg & 63u);
            const float4* cr = (const float4*)(cent + (size_t)col * DD);
            const float4 b0 = cr[l * 2], b1 = cr[l * 2 + 1];
            float s = 0.f;
            s = fmaf(a0.x, b0.x, s); s = fmaf(a0.y, b0.y, s);
            s = fmaf(a0.z, b0.z, s); s = fmaf(a0.w, b0.w, s);
            s = fmaf(a1.x, b1.x, s); s = fmaf(a1.y, b1.y, s);
            s = fmaf(a1.z, b1.z, s); s = fmaf(a1.w, b1.w, s);
#pragma unroll
            for (int off = 1; off < 64; off <<= 1) s += __shfl_xor(s, off, 64);
            const float dist = fmaf(-2.f, s, csq[col]);
            const unsigned long long key =
                ((unsigned long long)ordenc(dist) << 32) | (unsigned)col;
            best = (key < best) ? key : best;
        } else {
            const int cl = l >> 1, sg = l & 1;
            const float4* xh = (const float4*)(x + (size_t)row * DD + sg * 256);
            unsigned long long kb = ~0ull;
#pragma unroll
            for (int pass = 0; pass < 2; ++pass) {
                const int col = g * 64 + pass * 32 + cl;
                const float4* ch = (const float4*)(cent + (size_t)col * DD + sg * 256);
                float s0 = 0.f, s1 = 0.f, s2 = 0.f, s3 = 0.f;
#pragma unroll 8
                for (int ee = 0; ee < 64; ++ee) {
                    const float4 a = xh[ee], b = ch[ee];
                    s0 = fmaf(a.x, b.x, s0);
                    s1 = fmaf(a.y, b.y, s1);
                    s2 = fmaf(a.z, b.z, s2);
                    s3 = fmaf(a.w, b.w, s3);
                }
                float s = (s0 + s1) + (s2 + s3);
                s += __shfl_xor(s, 1, 64);
                const float dist = fmaf(-2.f, s, csq[col]);
                const unsigned long long key =
                    ((unsigned long long)ordenc(dist) << 32) | (unsigned)col;
                kb = (key < kb) ? key : kb;
            }
#pragma unroll
            for (int off = 1; off < 64; off <<= 1) {
                const unsigned long long o = __shfl_xor(kb, off, 64);
                kb = (o < kb) ? o : kb;
            }
            best = (kb < best) ? kb : best;
        }
    }
    if (l == 0) out[row] = (int)(best & 0xFFFFFFFFull);
}

// ---------------- fallback: round-1 fp32 kernel (proven) ----------------
__global__ __launch_bounds__(256) void argmin_fp32_kernel(
        const float* __restrict__ x, const float* __restrict__ cent,
        const float* __restrict__ csq, int* __restrict__ out) {
    __shared__ float xs[16][68];
    __shared__ float cs[16][132];
    const int tid = threadIdx.x;
    const int tx = tid & 15;
    const int ty = tid >> 4;
    const int m0 = blockIdx.x * 64;
    const int srow = tid >> 2;
    const int scol = (tid & 3) << 2;
    const float* xg  = x + (size_t)(m0 + srow) * DD + scol;
    const float* cgA = cent + (size_t)srow * DD + scol;
    const float* cgB = cent + (size_t)(srow + 64) * DD + scol;
    float best[4];
    int bidx[4];
#pragma unroll
    for (int i = 0; i < 4; ++i) { best[i] = INFINITY; bidx[i] = 0; }
    for (int n0 = 0; n0 < KC; n0 += 128) {
        float acc[4][2][4];
#pragma unroll
        for (int i = 0; i < 4; ++i)
#pragma unroll
            for (int h = 0; h < 2; ++h)
#pragma unroll
                for (int j = 0; j < 4; ++j) acc[i][h][j] = 0.f;
        const size_t nOff = (size_t)n0 * DD;
        float4 rx = *(const float4*)(xg);
        float4 rc0 = *(const float4*)(cgA + nOff);
        float4 rc1 = *(const float4*)(cgB + nOff);
        for (int k0 = 0; k0 < DD; k0 += 16) {
            __syncthreads();
            const float* p = (const float*)&rx;
            xs[scol + 0][srow] = p[0]; xs[scol + 1][srow] = p[1];
            xs[scol + 2][srow] = p[2]; xs[scol + 3][srow] = p[3];
            const float* q0 = (const float*)&rc0;
            cs[scol + 0][srow] = q0[0]; cs[scol + 1][srow] = q0[1];
            cs[scol + 2][srow] = q0[2]; cs[scol + 3][srow] = q0[3];
            const float* q1 = (const float*)&rc1;
            cs[scol + 0][srow + 64] = q1[0]; cs[scol + 1][srow + 64] = q1[1];
            cs[scol + 2][srow + 64] = q1[2]; cs[scol + 3][srow + 64] = q1[3];
            __syncthreads();
            if (k0 + 16 < DD) {
                rx  = *(const float4*)(xg + k0 + 16);
                rc0 = *(const float4*)(cgA + nOff + k0 + 16);
                rc1 = *(const float4*)(cgB + nOff + k0 + 16);
            }
#pragma unroll
            for (int dd = 0; dd < 16; ++dd) {
                float4 av  = *(const float4*)&xs[dd][ty << 2];
                float4 bv0 = *(const float4*)&cs[dd][tx << 2];
                float4 bv1 = *(const float4*)&cs[dd][64 + (tx << 2)];
                const float* a  = (const float*)&av;
                const float* b0 = (const float*)&bv0;
                const float* b1 = (const float*)&bv1;
#pragma unroll
                for (int i = 0; i < 4; ++i)
#pragma unroll
                    for (int j = 0; j < 4; ++j) {
                        acc[i][0][j] = fmaf(a[i], b0[j], acc[i][0][j]);
                        acc[i][1][j] = fmaf(a[i], b1[j], acc[i][1][j]);
                    }
            }
        }
        float4 qv0 = *(const float4*)(csq + n0 + (tx << 2));
        float4 qv1 = *(const float4*)(csq + n0 + 64 + (tx << 2));
        const float* q0 = (const float*)&qv0;
        const float* q1 = (const float*)&qv1;
#pragma unroll
        for (int i = 0; i < 4; ++i)
#pragma unroll
            for (int h = 0; h < 2; ++h)
#pragma unroll
                for (int j = 0; j < 4; ++j) {
                    float qq = (h == 0) ? q0[j] : q1[j];
                    float dist = fmaf(-2.f, acc[i][h][j], qq);
                    int kk = n0 + h * 64 + (tx << 2) + j;
                    if (dist < best[i] || (dist == best[i] && kk < bidx[i])) {
                        best[i] = dist; bidx[i] = kk;
                    }
                }
    }
#pragma unroll
    for (int off = 1; off < 16; off <<= 1)
#pragma unroll
        for (int i = 0; i < 4; ++i) {
            float ov = __shfl_xor(best[i], off, 64);
            int oi = __shfl_xor(bidx[i], off, 64);
            if (ov < best[i] || (ov == best[i] && oi < bidx[i])) {
                best[i] = ov; bidx[i] = oi;
            }
        }
    if (tx == 0)
#pragma unroll
        for (int i = 0; i < 4; ++i) out[m0 + (ty << 2) + i] = bidx[i];
}

extern "C" void kernel_launch(void* const* d_in, const int* in_sizes, int n_in,
                              void* d_out, int out_size, void* d_ws, size_t ws_size,
                              hipStream_t stream) {
    const float* x    = (const float*)d_in[0];
    const float* cent = (const float*)d_in[1];
    int* out = (int*)d_out;

    const size_t xb_bytes     = (size_t)NB * DD * 2;        // 32MB
    const size_t cb_bytes     = (size_t)KC * DD * 2;        // 4MB
    const size_t locmin_bytes = (size_t)NB * 64 * 8;        // 16MB (u64)
    const size_t csq_bytes    = (size_t)KC * 4;             // 16KB
    const size_t need = xb_bytes + cb_bytes + locmin_bytes + csq_bytes;

    if (ws_size >= need) {
        char* p = (char*)d_ws;
        unsigned short* xbT = (unsigned short*)p;              p += xb_bytes;
        unsigned short* cbT = (unsigned short*)p;              p += cb_bytes;
        unsigned long long* locmin64 = (unsigned long long*)p; p += locmin_bytes;
        float* csq = (float*)p;

        tileA_kernel<<<NB * DD / 8 / 256, 256, 0, stream>>>(x, xbT);
        tileB_kernel<<<KC * DD / 8 / 256, 256, 0, stream>>>(cent, cbT);
        csq_kernel<<<KC / 4, 256, 0, stream>>>(cent, csq);
        gemm_min<<<(NB / 256) * (KC / 256), 512, 0, stream>>>(xbT, cbT, csq, locmin64);
        rescue_argmin_kernel<<<NB / 4, 256, 0, stream>>>(x, cent, csq, locmin64, out);
    } else {
        float* csq = (float*)d_ws;
        csq_kernel<<<KC / 4, 256, 0, stream>>>(cent, csq);
        argmin_fp32_kernel<<<NB / 64, 256, 0, stream>>>(x, cent, csq, out);
    }
}

// Round 14
// 231.896 us; speedup vs baseline: 2.0801x; 1.1580x over previous
//
#include <hip/hip_runtime.h>
#include <math.h>

#define NB 32768
#define KC 4096
#define DD 512
#define DELTA 2.0f

typedef __attribute__((ext_vector_type(8))) short short8;
typedef __attribute__((ext_vector_type(4))) float facc4;

#define AS1 __attribute__((address_space(1)))
#define AS3 __attribute__((address_space(3)))

__device__ __forceinline__ void gll16(const void* g, void* lds) {
    __builtin_amdgcn_global_load_lds((const AS1 unsigned*)g, (AS3 unsigned*)lds,
                                     16, 0, 0);
}

__device__ __forceinline__ unsigned short f2bf(float f) {
    unsigned u = __float_as_uint(f);
    u += 0x7FFFu + ((u >> 16) & 1u);     // RNE
    return (unsigned short)(u >> 16);
}
__device__ __forceinline__ unsigned ordenc(float f) {
    unsigned u = __float_as_uint(f);
    return (u & 0x80000000u) ? ~u : (u | 0x80000000u);
}
__device__ __forceinline__ float orddec(unsigned o) {
    unsigned u = (o & 0x80000000u) ? (o & 0x7FFFFFFFu) : ~o;
    return __uint_as_float(u);
}
__device__ __forceinline__ unsigned umn(unsigned a, unsigned b) { return a < b ? a : b; }
__device__ __forceinline__ unsigned umx(unsigned a, unsigned b) { return a > b ? a : b; }

// DPP row_ror:N over 16-lane rows — VALU-only lane rotate (no LDS pipe).
#define ROR1(v) ((unsigned)__builtin_amdgcn_update_dpp((int)(v), (int)(v), 0x121, 0xF, 0xF, false))
#define ROR2(v) ((unsigned)__builtin_amdgcn_update_dpp((int)(v), (int)(v), 0x122, 0xF, 0xF, false))
#define ROR4(v) ((unsigned)__builtin_amdgcn_update_dpp((int)(v), (int)(v), 0x124, 0xF, 0xF, false))
#define ROR8(v) ((unsigned)__builtin_amdgcn_update_dpp((int)(v), (int)(v), 0x128, 0xF, 0xF, false))

// ---- A: fp32 -> bf16, tile to [mb(256rows)][ks8][kk2][256 r][32 d] ----
// 4-granule XOR swizzle (r11-proven, 0 conflicts): granule g at g ^ ((r>>1)&3)
__global__ __launch_bounds__(256) void tileA_kernel(const float* __restrict__ in,
                                                    unsigned short* __restrict__ out) {
    const size_t t = (size_t)blockIdx.x * 256 + threadIdx.x;
    const int row = (int)(t >> 6);
    const int d0  = (int)(t & 63) << 3;
    const int mb = row >> 8, r = row & 255;
    const int ks = d0 >> 6, kk = (d0 & 63) >> 5, dw = d0 & 31;
    const int g  = dw >> 3;
    const int dws = ((g ^ ((r >> 1) & 3)) << 3);
    const float4* p = (const float4*)(in + (size_t)row * DD + d0);
    float4 a = p[0], b = p[1];
    unsigned q0 = (unsigned)f2bf(a.x) | ((unsigned)f2bf(a.y) << 16);
    unsigned q1 = (unsigned)f2bf(a.z) | ((unsigned)f2bf(a.w) << 16);
    unsigned q2 = (unsigned)f2bf(b.x) | ((unsigned)f2bf(b.y) << 16);
    unsigned q3 = (unsigned)f2bf(b.z) | ((unsigned)f2bf(b.w) << 16);
    const size_t o = (((size_t)((mb * 8 + ks) * 2 + kk)) * 256 + r) * 32 + dws;
    *(uint4*)(out + o) = make_uint4(q0, q1, q2, q3);
}

// ---- B: same layout for centroids: [nb(256cols)][ks8][kk2][256][32] ----
__global__ __launch_bounds__(256) void tileB_kernel(const float* __restrict__ in,
                                                    unsigned short* __restrict__ out) {
    const size_t t = (size_t)blockIdx.x * 256 + threadIdx.x;
    const int row = (int)(t >> 6);
    const int d0  = (int)(t & 63) << 3;
    const int nb = row >> 8, r = row & 255;
    const int ks = d0 >> 6, kk = (d0 & 63) >> 5, dw = d0 & 31;
    const int g  = dw >> 3;
    const int dws = ((g ^ ((r >> 1) & 3)) << 3);
    const float4* p = (const float4*)(in + (size_t)row * DD + d0);
    float4 a = p[0], b = p[1];
    unsigned q0 = (unsigned)f2bf(a.x) | ((unsigned)f2bf(a.y) << 16);
    unsigned q1 = (unsigned)f2bf(a.z) | ((unsigned)f2bf(a.w) << 16);
    unsigned q2 = (unsigned)f2bf(b.x) | ((unsigned)f2bf(b.y) << 16);
    unsigned q3 = (unsigned)f2bf(b.z) | ((unsigned)f2bf(b.w) << 16);
    const size_t o = (((size_t)((nb * 8 + ks) * 2 + kk)) * 256 + r) * 32 + dws;
    *(uint4*)(out + o) = make_uint4(q0, q1, q2, q3);
}

// ---------------- c_sq[k] = sum_d c[k][d]^2 (fp32) ----------------
__global__ __launch_bounds__(256) void csq_kernel(const float* __restrict__ cent,
                                                  float* __restrict__ csq) {
    const int wid  = threadIdx.x >> 6;
    const int lane = threadIdx.x & 63;
    const int k = (blockIdx.x << 2) + wid;
    const float* row = cent + (size_t)k * DD;
    float s = 0.f;
#pragma unroll
    for (int d = 0; d < DD; d += 64) {
        float v = row[d + lane];
        s = fmaf(v, v, s);
    }
#pragma unroll
    for (int off = 32; off > 0; off >>= 1) s += __shfl_xor(s, off, 64);
    if (lane == 0) csq[k] = s;
}

// ---- 8-phase 256x256 bf16 MFMA GEMM (T3+T4+T5), 8 waves, 128KB LDS ----
// locmin64[row][64] u64 = { m1key:32 | m2key:32 } where key = ordenc(dist)&~63 | col6
__global__ __launch_bounds__(512, 2) void gemm_min(
    const unsigned short* __restrict__ xbT, const unsigned short* __restrict__ cbT,
    const float* __restrict__ csq, unsigned long long* __restrict__ locmin64)
{
    __shared__ unsigned short Al[2][2][8192];   // [buf][kkhalf][256r x 32d] 64KB
    __shared__ unsigned short Bl[2][2][8192];   // 64KB

    const int tid = threadIdx.x;
    const int l = tid & 63, w = tid >> 6;       // 8 waves
    const int wm = w >> 2, wn = w & 3;          // 2M x 4N wave grid
    const int hi = l >> 4, ln = l & 15;
    const int koh = (hi ^ ((ln & 7) >> 1)) << 3;

    const int bid = blockIdx.x;
    const int swz = (bid & 7) * 256 + (bid >> 3);   // bijective XCD swizzle
    const int nb = swz >> 7, mb = swz & 127;

    const int aoff = (wm * 128 + ln) * 32 + koh;
    const int boff = (wn * 64 + ln) * 32 + koh;

#define SA(ks_, kk_) do {                                                     \
    const unsigned short* s_ = xbT +                                          \
        ((size_t)((mb * 8 + (ks_)) * 2 + (kk_))) * 8192 + w * 512 + l * 8;    \
    unsigned short* d_ = &Al[(ks_) & 1][(kk_)][w * 512];                      \
    gll16(s_, d_); gll16(s_ + 4096, d_ + 4096); } while (0)
#define SB(ks_, kk_) do {                                                     \
    const unsigned short* s_ = cbT +                                          \
        ((size_t)((nb * 8 + (ks_)) * 2 + (kk_))) * 8192 + w * 512 + l * 8;    \
    unsigned short* d_ = &Bl[(ks_) & 1][(kk_)][w * 512];                      \
    gll16(s_, d_); gll16(s_ + 4096, d_ + 4096); } while (0)
#define BAR  asm volatile("s_barrier" ::: "memory")
#define VBAR asm volatile("s_waitcnt vmcnt(6)\ns_barrier" ::: "memory")

    facc4 acc[8][4];
#pragma unroll
    for (int fr = 0; fr < 8; ++fr)
#pragma unroll
        for (int fc = 0; fc < 4; ++fc) {
            facc4 z = {0.f, 0.f, 0.f, 0.f};
            acc[fr][fc] = z;
        }

    // prologue: K0 fully + K1 {Bkk0, Akk0, Bkk1}; K1.Akk1 comes at K0.p0
    SA(0, 0); SB(0, 0); SA(0, 1); SB(0, 1);
    SB(1, 0); SA(1, 0); SB(1, 1);
    VBAR;   // K0 landed; 3 halves of K1 in flight

    short8 bv[4];

#define LOADA(b_, kk_, frb_)                                                  \
    _Pragma("unroll")                                                         \
    for (int f2 = 0; f2 < 4; ++f2)                                            \
        av[f2] = *(const short8*)&Al[b_][kk_][aoff + ((frb_) + f2) * 512];
#define LOADB(b_, kk_)                                                        \
    _Pragma("unroll")                                                         \
    for (int fc = 0; fc < 4; ++fc)                                            \
        bv[fc] = *(const short8*)&Bl[b_][kk_][boff + fc * 512];
#define MFMA16(frb_)                                                          \
    __builtin_amdgcn_s_setprio(1);                                            \
    _Pragma("unroll")                                                         \
    for (int f2 = 0; f2 < 4; ++f2)                                            \
        _Pragma("unroll")                                                     \
        for (int fc = 0; fc < 4; ++fc)                                        \
            acc[(frb_) + f2][fc] = __builtin_amdgcn_mfma_f32_16x16x32_bf16(   \
                av[f2], bv[fc], acc[(frb_) + f2][fc], 0, 0, 0);               \
    __builtin_amdgcn_s_setprio(0);

#pragma unroll 1
    for (int kp = 0; kp < 4; ++kp) {
        const bool st = (kp < 3);
        const int ks0 = 2 * kp;
        // ======== K-tile ks0 (buf 0) ========
        { short8 av[4]; LOADA(0, 0, 0) LOADB(0, 0)       // p0
          SA(ks0 + 1, 1);                                // completes K-tile ks0+1
          BAR; MFMA16(0) BAR; }
        { short8 av[4]; LOADA(0, 0, 4)                   // p1 (bv reuse)
          if (st) SB(ks0 + 2, 0);
          BAR; MFMA16(4) BAR; }
        { short8 av[4]; LOADA(0, 1, 0) LOADB(0, 1)       // p2
          if (st) SA(ks0 + 2, 0);
          BAR; MFMA16(0) BAR; }
        { short8 av[4]; LOADA(0, 1, 4)                   // p3
          if (st) SB(ks0 + 2, 1);
          BAR; MFMA16(4) VBAR; }                         // next K-tile ready
        // ======== K-tile ks0+1 (buf 1) ========
        { short8 av[4]; LOADA(1, 0, 0) LOADB(1, 0)       // p4
          if (st) SA(ks0 + 2, 1);
          BAR; MFMA16(0) BAR; }
        { short8 av[4]; LOADA(1, 0, 4)                   // p5
          if (st) SB(ks0 + 3, 0);
          BAR; MFMA16(4) BAR; }
        { short8 av[4]; LOADA(1, 1, 0) LOADB(1, 1)       // p6
          if (st) SA(ks0 + 3, 0);
          BAR; MFMA16(0) BAR; }
        { short8 av[4]; LOADA(1, 1, 4)                   // p7
          if (st) SB(ks0 + 3, 1);
          BAR; MFMA16(4) VBAR; }
    }

    // ---- epilogue v2: key-packed min/min2, DPP row_ror reduce (zero LDS) ----
    const int n0 = nb * 256;
    const int grp = nb * 4 + wn;
    float cs4[4];
#pragma unroll
    for (int fc = 0; fc < 4; ++fc) cs4[fc] = csq[n0 + wn * 64 + fc * 16 + ln];

#pragma unroll
    for (int fr = 0; fr < 8; ++fr) {
#pragma unroll
        for (int j = 0; j < 4; ++j) {
            // keys: ordenc(dist) with low 6 bits = col-in-group (total order,
            // <=63-ulp value noise, absorbed by DELTA slack)
            const unsigned k0 = (ordenc(fmaf(-2.f, acc[fr][0][j], cs4[0])) & ~63u) | (unsigned)(0 * 16 + ln);
            const unsigned k1 = (ordenc(fmaf(-2.f, acc[fr][1][j], cs4[1])) & ~63u) | (unsigned)(1 * 16 + ln);
            const unsigned k2 = (ordenc(fmaf(-2.f, acc[fr][2][j], cs4[2])) & ~63u) | (unsigned)(2 * 16 + ln);
            const unsigned k3 = (ordenc(fmaf(-2.f, acc[fr][3][j], cs4[3])) & ~63u) | (unsigned)(3 * 16 + ln);
            const unsigned lo01 = umn(k0, k1), hi01 = umx(k0, k1);
            const unsigned lo23 = umn(k2, k3), hi23 = umx(k2, k3);
            unsigned m1k = umn(lo01, lo23);
            unsigned m2k = umn(umn(hi01, hi23), umx(lo01, lo23));
            // 16-lane rotation reduce, disjoint-set min2 merge each step
            { const unsigned o1 = ROR1(m1k), o2 = ROR1(m2k);
              m2k = umn(umn(m2k, o2), umx(m1k, o1)); m1k = umn(m1k, o1); }
            { const unsigned o1 = ROR2(m1k), o2 = ROR2(m2k);
              m2k = umn(umn(m2k, o2), umx(m1k, o1)); m1k = umn(m1k, o1); }
            { const unsigned o1 = ROR4(m1k), o2 = ROR4(m2k);
              m2k = umn(umn(m2k, o2), umx(m1k, o1)); m1k = umn(m1k, o1); }
            { const unsigned o1 = ROR8(m1k), o2 = ROR8(m2k);
              m2k = umn(umn(m2k, o2), umx(m1k, o1)); m1k = umn(m1k, o1); }
            if (ln == 0) {
                const int row = mb * 256 + wm * 128 + fr * 16 + hi * 4 + j;
                locmin64[(size_t)row * 64 + grp] =
                    ((unsigned long long)m1k << 32) | m2k;
            }
        }
    }
#undef SA
#undef SB
#undef BAR
#undef VBAR
#undef LOADA
#undef LOADB
#undef MFMA16
}

// ---- fused rowthr+qualify+rescue+finalize: one wave per row, zero atomics ----
__global__ __launch_bounds__(256) void rescue_argmin_kernel(
    const float* __restrict__ x, const float* __restrict__ cent,
    const float* __restrict__ csq,
    const unsigned long long* __restrict__ locmin64, int* __restrict__ out)
{
    const int row = blockIdx.x * 4 + (threadIdx.x >> 6);
    const int l = threadIdx.x & 63;

    const unsigned long long e = locmin64[(size_t)row * 64 + l];

    unsigned long long v = e;
#pragma unroll
    for (int off = 32; off > 0; off >>= 1) {
        const unsigned long long o = __shfl_xor(v, off, 64);
        v = (o < v) ? o : v;
    }
    const float thrf = orddec((unsigned)(v >> 32)) + DELTA;
    const unsigned thr_enc = ordenc(thrf);
    unsigned long long qmask = __ballot((unsigned)(e >> 32) <= thr_enc);

    const float4* xr = (const float4*)(x + (size_t)row * DD);
    const float4 a0 = xr[l * 2];
    const float4 a1 = xr[l * 2 + 1];

    unsigned long long best = ~0ull;
    while (qmask) {
        const int g = (int)__ffsll((long long)qmask) - 1;
        qmask &= qmask - 1;
        const unsigned long long eg = __shfl(e, g, 64);
        const unsigned m2k = (unsigned)eg;
        if (m2k > thr_enc) {
            // single-col: exact fp32 dot of the group's approx-argmin col
            const int col = g * 64 + (int)((eg >> 32) & 63u);
            const float4* cr = (const float4*)(cent + (size_t)col * DD);
            const float4 b0 = cr[l * 2], b1 = cr[l * 2 + 1];
            float s = 0.f;
            s = fmaf(a0.x, b0.x, s); s = fmaf(a0.y, b0.y, s);
            s = fmaf(a0.z, b0.z, s); s = fmaf(a0.w, b0.w, s);
            s = fmaf(a1.x, b1.x, s); s = fmaf(a1.y, b1.y, s);
            s = fmaf(a1.z, b1.z, s); s = fmaf(a1.w, b1.w, s);
#pragma unroll
            for (int off = 1; off < 64; off <<= 1) s += __shfl_xor(s, off, 64);
            const float dist = fmaf(-2.f, s, csq[col]);
            const unsigned long long key =
                ((unsigned long long)ordenc(dist) << 32) | (unsigned)col;
            best = (key < best) ? key : best;
        } else {
            // full-group (rare): exact fp32 dists for all 64 cols
            const int cl = l >> 1, sg = l & 1;
            const float4* xh = (const float4*)(x + (size_t)row * DD + sg * 256);
            unsigned long long kb = ~0ull;
#pragma unroll
            for (int pass = 0; pass < 2; ++pass) {
                const int col = g * 64 + pass * 32 + cl;
                const float4* ch = (const float4*)(cent + (size_t)col * DD + sg * 256);
                float s0 = 0.f, s1 = 0.f, s2 = 0.f, s3 = 0.f;
#pragma unroll 8
                for (int ee = 0; ee < 64; ++ee) {
                    const float4 a = xh[ee], b = ch[ee];
                    s0 = fmaf(a.x, b.x, s0);
                    s1 = fmaf(a.y, b.y, s1);
                    s2 = fmaf(a.z, b.z, s2);
                    s3 = fmaf(a.w, b.w, s3);
                }
                float s = (s0 + s1) + (s2 + s3);
                s += __shfl_xor(s, 1, 64);
                const float dist = fmaf(-2.f, s, csq[col]);
                const unsigned long long key =
                    ((unsigned long long)ordenc(dist) << 32) | (unsigned)col;
                kb = (key < kb) ? key : kb;
            }
#pragma unroll
            for (int off = 1; off < 64; off <<= 1) {
                const unsigned long long o = __shfl_xor(kb, off, 64);
                kb = (o < kb) ? o : kb;
            }
            best = (kb < best) ? kb : best;
        }
    }
    if (l == 0) out[row] = (int)(best & 0xFFFFFFFFull);
}

// ---------------- fallback: round-1 fp32 kernel (proven) ----------------
__global__ __launch_bounds__(256) void argmin_fp32_kernel(
        const float* __restrict__ x, const float* __restrict__ cent,
        const float* __restrict__ csq, int* __restrict__ out) {
    __shared__ float xs[16][68];
    __shared__ float cs[16][132];
    const int tid = threadIdx.x;
    const int tx = tid & 15;
    const int ty = tid >> 4;
    const int m0 = blockIdx.x * 64;
    const int srow = tid >> 2;
    const int scol = (tid & 3) << 2;
    const float* xg  = x + (size_t)(m0 + srow) * DD + scol;
    const float* cgA = cent + (size_t)srow * DD + scol;
    const float* cgB = cent + (size_t)(srow + 64) * DD + scol;
    float best[4];
    int bidx[4];
#pragma unroll
    for (int i = 0; i < 4; ++i) { best[i] = INFINITY; bidx[i] = 0; }
    for (int n0 = 0; n0 < KC; n0 += 128) {
        float acc[4][2][4];
#pragma unroll
        for (int i = 0; i < 4; ++i)
#pragma unroll
            for (int h = 0; h < 2; ++h)
#pragma unroll
                for (int j = 0; j < 4; ++j) acc[i][h][j] = 0.f;
        const size_t nOff = (size_t)n0 * DD;
        float4 rx = *(const float4*)(xg);
        float4 rc0 = *(const float4*)(cgA + nOff);
        float4 rc1 = *(const float4*)(cgB + nOff);
        for (int k0 = 0; k0 < DD; k0 += 16) {
            __syncthreads();
            const float* p = (const float*)&rx;
            xs[scol + 0][srow] = p[0]; xs[scol + 1][srow] = p[1];
            xs[scol + 2][srow] = p[2]; xs[scol + 3][srow] = p[3];
            const float* q0 = (const float*)&rc0;
            cs[scol + 0][srow] = q0[0]; cs[scol + 1][srow] = q0[1];
            cs[scol + 2][srow] = q0[2]; cs[scol + 3][srow] = q0[3];
            const float* q1 = (const float*)&rc1;
            cs[scol + 0][srow + 64] = q1[0]; cs[scol + 1][srow + 64] = q1[1];
            cs[scol + 2][srow + 64] = q1[2]; cs[scol + 3][srow + 64] = q1[3];
            __syncthreads();
            if (k0 + 16 < DD) {
                rx  = *(const float4*)(xg + k0 + 16);
                rc0 = *(const float4*)(cgA + nOff + k0 + 16);
                rc1 = *(const float4*)(cgB + nOff + k0 + 16);
            }
#pragma unroll
            for (int dd = 0; dd < 16; ++dd) {
                float4 av  = *(const float4*)&xs[dd][ty << 2];
                float4 bv0 = *(const float4*)&cs[dd][tx << 2];
                float4 bv1 = *(const float4*)&cs[dd][64 + (tx << 2)];
                const float* a  = (const float*)&av;
                const float* b0 = (const float*)&bv0;
                const float* b1 = (const float*)&bv1;
#pragma unroll
                for (int i = 0; i < 4; ++i)
#pragma unroll
                    for (int j = 0; j < 4; ++j) {
                        acc[i][0][j] = fmaf(a[i], b0[j], acc[i][0][j]);
                        acc[i][1][j] = fmaf(a[i], b1[j], acc[i][1][j]);
                    }
            }
        }
        float4 qv0 = *(const float4*)(csq + n0 + (tx << 2));
        float4 qv1 = *(const float4*)(csq + n0 + 64 + (tx << 2));
        const float* q0 = (const float*)&qv0;
        const float* q1 = (const float*)&qv1;
#pragma unroll
        for (int i = 0; i < 4; ++i)
#pragma unroll
            for (int h = 0; h < 2; ++h)
#pragma unroll
                for (int j = 0; j < 4; ++j) {
                    float qq = (h == 0) ? q0[j] : q1[j];
                    float dist = fmaf(-2.f, acc[i][h][j], qq);
                    int kk = n0 + h * 64 + (tx << 2) + j;
                    if (dist < best[i] || (dist == best[i] && kk < bidx[i])) {
                        best[i] = dist; bidx[i] = kk;
                    }
                }
    }
#pragma unroll
    for (int off = 1; off < 16; off <<= 1)
#pragma unroll
        for (int i = 0; i < 4; ++i) {
            float ov = __shfl_xor(best[i], off, 64);
            int oi = __shfl_xor(bidx[i], off, 64);
            if (ov < best[i] || (ov == best[i] && oi < bidx[i])) {
                best[i] = ov; bidx[i] = oi;
            }
        }
    if (tx == 0)
#pragma unroll
        for (int i = 0; i < 4; ++i) out[m0 + (ty << 2) + i] = bidx[i];
}

extern "C" void kernel_launch(void* const* d_in, const int* in_sizes, int n_in,
                              void* d_out, int out_size, void* d_ws, size_t ws_size,
                              hipStream_t stream) {
    const float* x    = (const float*)d_in[0];
    const float* cent = (const float*)d_in[1];
    int* out = (int*)d_out;

    const size_t xb_bytes     = (size_t)NB * DD * 2;        // 32MB
    const size_t cb_bytes     = (size_t)KC * DD * 2;        // 4MB
    const size_t locmin_bytes = (size_t)NB * 64 * 8;        // 16MB (u64)
    const size_t csq_bytes    = (size_t)KC * 4;             // 16KB
    const size_t need = xb_bytes + cb_bytes + locmin_bytes + csq_bytes;

    if (ws_size >= need) {
        char* p = (char*)d_ws;
        unsigned short* xbT = (unsigned short*)p;              p += xb_bytes;
        unsigned short* cbT = (unsigned short*)p;              p += cb_bytes;
        unsigned long long* locmin64 = (unsigned long long*)p; p += locmin_bytes;
        float* csq = (float*)p;

        tileA_kernel<<<NB * DD / 8 / 256, 256, 0, stream>>>(x, xbT);
        tileB_kernel<<<KC * DD / 8 / 256, 256, 0, stream>>>(cent, cbT);
        csq_kernel<<<KC / 4, 256, 0, stream>>>(cent, csq);
        gemm_min<<<(NB / 256) * (KC / 256), 512, 0, stream>>>(xbT, cbT, csq, locmin64);
        rescue_argmin_kernel<<<NB / 4, 256, 0, stream>>>(x, cent, csq, locmin64, out);
    } else {
        float* csq = (float*)d_ws;
        csq_kernel<<<KC / 4, 256, 0, stream>>>(cent, csq);
        argmin_fp32_kernel<<<NB / 64, 256, 0, stream>>>(x, cent, csq, out);
    }
}